// Round 4
// baseline (687.595 us; speedup 1.0000x reference)
//
#include <hip/hip_runtime.h>
#include <math.h>

#define D_ 96
#define L_ 4096
#define K_ 8
#define N_ 16
#define R_ 6
#define CDBL 38   // R + 2N
#define DL_ (D_ * L_)

#define REP16(M) M(0) M(1) M(2) M(3) M(4) M(5) M(6) M(7) \
                 M(8) M(9) M(10) M(11) M(12) M(13) M(14) M(15)
#define REP4(M) M(0) M(1) M(2) M(3)

__device__ __forceinline__ float softplusf(float x) {
    return (x > 20.f) ? x : log1pf(__expf(x));
}

// source index within one channel's [64][64] image for direction k, flat pos l
__device__ __forceinline__ int src_index(int k, int l) {
    int h = l & 63, w = l >> 6;
    int lp = 4095 - l;
    int hp = lp & 63, wp = lp >> 6;
    switch (k) {
    case 0: return l;
    case 1: return (h << 6) + w;
    case 2: return lp;
    case 3: return (hp << 6) + wp;
    case 4: return (h << 6) + ((h + w) & 63);
    case 5: return (h << 6) + ((w - h) & 63);
    case 6: return (hp << 6) + ((hp + wp) & 63);
    default: return (hp << 6) + ((wp - hp) & 63);
    }
}

// ---------------- K_A: x_dbl = wproj @ cross_scan(x), gathers x inline ----------
// grid 512 = 8 k * 64 l-tiles of 64; block 256
__global__ __launch_bounds__(256) void k_xdbl(const float* __restrict__ x,
                                              const float* __restrict__ wproj,
                                              float* __restrict__ xdbl) {
    __shared__ float tile[64][100];     // [li][d], stride 100 -> b128 reads conflict-free
    __shared__ float wlds[40 * D_];     // padded to 40 rows, rows 38/39 zero
    int bid = blockIdx.x;
    int swz = (bid & 7) * 64 + (bid >> 3);   // XCD swizzle: each XCD owns one k
    int k = swz >> 6;
    int l0 = (swz & 63) * 64;

    for (int e = threadIdx.x; e < 40 * D_; e += 256)
        wlds[e] = (e < CDBL * D_) ? wproj[k * CDBL * D_ + e] : 0.f;
    for (int e = threadIdx.x; e < D_ * 64; e += 256) {
        int d = e >> 6, li = e & 63;
        tile[li][d] = x[d * L_ + src_index(k, l0 + li)];
    }
    __syncthreads();

    int lt = threadIdx.x & 63;
    int cg = threadIdx.x >> 6;          // 0..3
    float acc[10];
    #pragma unroll
    for (int j = 0; j < 10; ++j) acc[j] = 0.f;
    for (int d4 = 0; d4 < D_; d4 += 4) {
        float4 tv = *(const float4*)&tile[lt][d4];
        #pragma unroll
        for (int j = 0; j < 10; ++j) {
            int c = cg + 4 * j;
            float4 wv = *(const float4*)&wlds[c * D_ + d4];
            acc[j] = fmaf(tv.x, wv.x, acc[j]);
            acc[j] = fmaf(tv.y, wv.y, acc[j]);
            acc[j] = fmaf(tv.z, wv.z, acc[j]);
            acc[j] = fmaf(tv.w, wv.w, acc[j]);
        }
    }
    #pragma unroll
    for (int j = 0; j < 10; ++j) {
        int c = cg + 4 * j;
        if (c < CDBL) xdbl[(k * CDBL + c) * L_ + l0 + lt] = acc[j];
    }
}

// ---------------- K_B: fused delta + selective scan ----------------
// grid 768 (one (k,d) chain per block, k == XCD id). Block 256; thread t owns
// l in [16t,16t+16). All hot arrays are accessed ONLY via REP16 macros with
// literal indices: rounds 2/3 showed #pragma unroll was dropped on the big
// n-loop bodies -> runtime-indexed arrays -> scratch (517MB FETCH, VGPR=84).

#if __has_builtin(__builtin_amdgcn_update_dpp)
#define HAVE_DPP 1
template<int CTRL, int RM>
__device__ __forceinline__ float updpp(float oldv, float src) {
    int r = __builtin_amdgcn_update_dpp(__builtin_bit_cast(int, oldv),
                                        __builtin_bit_cast(int, src),
                                        CTRL, RM, 0xF, false);
    return __builtin_bit_cast(float, r);
}
#else
#define HAVE_DPP 0
#endif

template<int CTRL, int RM>
__device__ __forceinline__ void scan_stage(float (&Aa)[16], float (&Ba)[16]) {
#if HAVE_DPP
#define PB(n) { float pa = updpp<CTRL, RM>(1.f, Aa[n]); \
                float pb = updpp<CTRL, RM>(0.f, Ba[n]); \
                Ba[n] = fmaf(Aa[n], pb, Ba[n]); Aa[n] *= pa; }
    REP16(PB)
#undef PB
#endif
}

__global__ __launch_bounds__(256, 3) void k_scan(const float* __restrict__ xdbl,
                                                 const float* __restrict__ dtw,
                                                 const float* __restrict__ dtb,
                                                 const float* __restrict__ alogs,
                                                 const float* __restrict__ dsv_,
                                                 const float* __restrict__ x,
                                                 float* __restrict__ ys) {
    int bid = blockIdx.x;
    int k = bid & 7;                 // XCD swizzle: k == XCD id
    int d = bid >> 3;
    int kd = k * D_ + d;
    int t = threadIdx.x;
    int lane = t & 63, wv = t >> 6;
    int l0t = t * 16;

    __shared__ float An_s[16];
    __shared__ float agg_a[4][16], agg_b[4][16];
    if (t < 16) An_s[t] = -expf(alogs[kd * N_ + t]);

    float d16[16], u16[16], y16[16], Aa[16], Ba[16];

    // ---- delta (fused): three aligned float2 loads of dtw row ----
    const float* xr = xdbl + k * CDBL * L_;
    const float2* wp2 = (const float2*)(dtw + kd * R_);   // kd*24B: 8B-aligned
    const float2 w01 = wp2[0], w23 = wp2[1], w45 = wp2[2];
    const float bias = dtb[kd];
#define DLT(j) { \
    const float4 r0 = *(const float4*)(xr + 0 * L_ + l0t + j * 4); \
    const float4 r1 = *(const float4*)(xr + 1 * L_ + l0t + j * 4); \
    const float4 r2 = *(const float4*)(xr + 2 * L_ + l0t + j * 4); \
    const float4 r3 = *(const float4*)(xr + 3 * L_ + l0t + j * 4); \
    const float4 r4 = *(const float4*)(xr + 4 * L_ + l0t + j * 4); \
    const float4 r5 = *(const float4*)(xr + 5 * L_ + l0t + j * 4); \
    float s; \
    s = fmaf(w01.x, r0.x, bias); s = fmaf(w01.y, r1.x, s); s = fmaf(w23.x, r2.x, s); \
    s = fmaf(w23.y, r3.x, s); s = fmaf(w45.x, r4.x, s); s = fmaf(w45.y, r5.x, s); \
    d16[j * 4 + 0] = softplusf(s); \
    s = fmaf(w01.x, r0.y, bias); s = fmaf(w01.y, r1.y, s); s = fmaf(w23.x, r2.y, s); \
    s = fmaf(w23.y, r3.y, s); s = fmaf(w45.x, r4.y, s); s = fmaf(w45.y, r5.y, s); \
    d16[j * 4 + 1] = softplusf(s); \
    s = fmaf(w01.x, r0.z, bias); s = fmaf(w01.y, r1.z, s); s = fmaf(w23.x, r2.z, s); \
    s = fmaf(w23.y, r3.z, s); s = fmaf(w45.x, r4.z, s); s = fmaf(w45.y, r5.z, s); \
    d16[j * 4 + 2] = softplusf(s); \
    s = fmaf(w01.x, r0.w, bias); s = fmaf(w01.y, r1.w, s); s = fmaf(w23.x, r2.w, s); \
    s = fmaf(w23.y, r3.w, s); s = fmaf(w45.x, r4.w, s); s = fmaf(w45.y, r5.w, s); \
    d16[j * 4 + 3] = softplusf(s); }
    REP4(DLT)
#undef DLT

    // ---- u gather from x (x is 1.5MB -> L2/L3-resident) ----
    const float* xd = x + d * L_;
#define UG(i) u16[i] = xd[src_index(k, l0t + i)];
    REP16(UG)
#undef UG
#define YZ(i) y16[i] = 0.f;
    REP16(YZ)
#undef YZ

    __syncthreads();   // An_s ready

    const float* Bptr = xdbl + (k * CDBL + R_) * L_ + l0t;
    const float* Cptr = Bptr + N_ * L_;

    // ---- Phase A: local scan + bb-part of y ----
#define PHA_E(i, Bc, Cc) { float a = __expf(d16[i] * An); \
    float b = d16[i] * (Bc) * u16[i]; \
    rb = fmaf(a, rb, b); ra *= a; y16[i] = fmaf((Cc), rb, y16[i]); }
#define PHA(n) { \
    const float An = An_s[n]; \
    const float* Bn = Bptr + n * L_; const float* Cn = Cptr + n * L_; \
    const float4 Bv0 = *(const float4*)(Bn + 0), Bv1 = *(const float4*)(Bn + 4); \
    const float4 Bv2 = *(const float4*)(Bn + 8), Bv3 = *(const float4*)(Bn + 12); \
    const float4 Cv0 = *(const float4*)(Cn + 0), Cv1 = *(const float4*)(Cn + 4); \
    const float4 Cv2 = *(const float4*)(Cn + 8), Cv3 = *(const float4*)(Cn + 12); \
    float ra = 1.f, rb = 0.f; \
    PHA_E(0, Bv0.x, Cv0.x) PHA_E(1, Bv0.y, Cv0.y) PHA_E(2, Bv0.z, Cv0.z) PHA_E(3, Bv0.w, Cv0.w) \
    PHA_E(4, Bv1.x, Cv1.x) PHA_E(5, Bv1.y, Cv1.y) PHA_E(6, Bv1.z, Cv1.z) PHA_E(7, Bv1.w, Cv1.w) \
    PHA_E(8, Bv2.x, Cv2.x) PHA_E(9, Bv2.y, Cv2.y) PHA_E(10, Bv2.z, Cv2.z) PHA_E(11, Bv2.w, Cv2.w) \
    PHA_E(12, Bv3.x, Cv3.x) PHA_E(13, Bv3.y, Cv3.y) PHA_E(14, Bv3.z, Cv3.z) PHA_E(15, Bv3.w, Cv3.w) \
    Aa[n] = ra; Ba[n] = rb; }
    REP16(PHA)
#undef PHA
#undef PHA_E

    // ---- Phase B: 64-lane inclusive scan of 16 (a,b) pairs (batched, VALU) ----
#if HAVE_DPP
    scan_stage<0x111, 0xF>(Aa, Ba);   // row_shr:1
    scan_stage<0x112, 0xF>(Aa, Ba);   // row_shr:2
    scan_stage<0x114, 0xF>(Aa, Ba);   // row_shr:4
    scan_stage<0x118, 0xF>(Aa, Ba);   // row_shr:8
    scan_stage<0x142, 0xA>(Aa, Ba);   // row_bcast:15 -> rows 1,3
    scan_stage<0x143, 0xC>(Aa, Ba);   // row_bcast:31 -> rows 2,3
#else
#define PBF(n) { float pa = __shfl_up(Aa[n], off); float pb = __shfl_up(Ba[n], off); \
    if (lane >= off) { Ba[n] = fmaf(Aa[n], pb, Ba[n]); Aa[n] *= pa; } }
    for (int off = 1; off < 64; off <<= 1) { REP16(PBF) }
#undef PBF
#endif

    // exclusive prefix per lane + wave aggregates
#define PPREF(n) { float ia = Aa[n], ib = Ba[n]; \
    float ea = __shfl_up(ia, 1); float eb = __shfl_up(ib, 1); \
    if (lane == 0) { ea = 1.f; eb = 0.f; } \
    if (lane == 63) { agg_a[wv][n] = ia; agg_b[wv][n] = ib; } \
    Aa[n] = ea; Ba[n] = eb; }
    REP16(PPREF)
#undef PPREF
    __syncthreads();

    // ---- Phase C: cross-wave carry -> h0 per (thread, n) ----
#define PC(n) { float cb = 0.f; \
    for (int w2 = 0; w2 < wv; ++w2) cb = fmaf(agg_a[w2][n], cb, agg_b[w2][n]); \
    Aa[n] = fmaf(Aa[n], cb, Ba[n]); }
    REP16(PC)
#undef PC

    // ---- Phase D: y += C * aa * h0 (exp-only recompute) ----
#define PHD_E(i, Cc) { aa *= __expf(d16[i] * An); y16[i] = fmaf((Cc) * aa, h0, y16[i]); }
#define PHD(n) { \
    const float An = An_s[n]; const float h0 = Aa[n]; \
    const float* Cn = Cptr + n * L_; \
    const float4 Cv0 = *(const float4*)(Cn + 0), Cv1 = *(const float4*)(Cn + 4); \
    const float4 Cv2 = *(const float4*)(Cn + 8), Cv3 = *(const float4*)(Cn + 12); \
    float aa = 1.f; \
    PHD_E(0, Cv0.x) PHD_E(1, Cv0.y) PHD_E(2, Cv0.z) PHD_E(3, Cv0.w) \
    PHD_E(4, Cv1.x) PHD_E(5, Cv1.y) PHD_E(6, Cv1.z) PHD_E(7, Cv1.w) \
    PHD_E(8, Cv2.x) PHD_E(9, Cv2.y) PHD_E(10, Cv2.z) PHD_E(11, Cv2.w) \
    PHD_E(12, Cv3.x) PHD_E(13, Cv3.y) PHD_E(14, Cv3.z) PHD_E(15, Cv3.w) }
    REP16(PHD)
#undef PHD
#undef PHD_E

    const float dval = dsv_[kd];
#define YD(i) y16[i] = fmaf(dval, u16[i], y16[i]);
    REP16(YD)
#undef YD
    float* yp = ys + kd * L_ + l0t;
#define YS(q) *(float4*)(yp + q * 4) = *(const float4*)&y16[q * 4];
    REP4(YS)
#undef YS
}

// ---------------- K_C: cross_merge + LayerNorm fused ----------------
// grid 128 blocks x 32 positions; block 256
__global__ __launch_bounds__(256) void k_merge_ln(const float* __restrict__ ys,
                                                  const float* __restrict__ gamma,
                                                  const float* __restrict__ beta,
                                                  float* __restrict__ out) {
    __shared__ float sm[32][D_ + 1];
    __shared__ float mu_s[32], rs_s[32];
    int l0 = blockIdx.x * 32;
    for (int e = threadIdx.x; e < 32 * D_; e += 256) {
        int li = e & 31, d = e >> 5;
        int l = l0 + li;
        int h = l >> 6, w = l & 63;
        int i1 = (w << 6) + h;
        int i4 = (((w - h) & 63) << 6) + h;
        int i5 = (((w + h) & 63) << 6) + h;
        const float* bd = ys + d * L_;
        float v = bd[0 * DL_ + l] + bd[2 * DL_ + 4095 - l]
                + bd[1 * DL_ + i1] + bd[3 * DL_ + 4095 - i1]
                + bd[4 * DL_ + i4] + bd[6 * DL_ + 4095 - i4]
                + bd[5 * DL_ + i5] + bd[7 * DL_ + 4095 - i5];
        sm[li][d] = v;
    }
    __syncthreads();
    int li2 = threadIdx.x >> 3, sub = threadIdx.x & 7;
    float s = 0.f, sq = 0.f;
    for (int d = sub; d < D_; d += 8) {
        float v = sm[li2][d];
        s += v; sq = fmaf(v, v, sq);
    }
    s += __shfl_xor(s, 1); sq += __shfl_xor(sq, 1);
    s += __shfl_xor(s, 2); sq += __shfl_xor(sq, 2);
    s += __shfl_xor(s, 4); sq += __shfl_xor(sq, 4);
    if (sub == 0) {
        float mu = s * (1.f / 96.f);
        float var = sq * (1.f / 96.f) - mu * mu;
        mu_s[li2] = mu;
        rs_s[li2] = rsqrtf(var + 1e-5f);
    }
    __syncthreads();
    for (int e = threadIdx.x; e < 32 * D_; e += 256) {
        int li = e / D_, d = e - li * D_;
        float v = (sm[li][d] - mu_s[li]) * rs_s[li];
        out[(l0 + li) * D_ + d] = fmaf(v, gamma[d], beta[d]);
    }
}

extern "C" void kernel_launch(void* const* d_in, const int* in_sizes, int n_in,
                              void* d_out, int out_size, void* d_ws, size_t ws_size,
                              hipStream_t stream) {
    const float* x     = (const float*)d_in[0];
    const float* wproj = (const float*)d_in[1];
    const float* dtw   = (const float*)d_in[2];
    const float* dtb   = (const float*)d_in[3];
    const float* alogs = (const float*)d_in[4];
    const float* dsv   = (const float*)d_in[5];
    const float* gamma = (const float*)d_in[6];
    const float* beta  = (const float*)d_in[7];
    float* out = (float*)d_out;
    float* ws  = (float*)d_ws;

    float* xdbl = ws;                 // K*CDBL*L = 1,245,184 floats
    float* ysb  = ws + 1245184;       // K*D*L    = 3,145,728 floats

    hipLaunchKernelGGL(k_xdbl, dim3(512), dim3(256), 0, stream, x, wproj, xdbl);
    hipLaunchKernelGGL(k_scan, dim3(768), dim3(256), 0, stream,
                       xdbl, dtw, dtb, alogs, dsv, x, ysb);
    hipLaunchKernelGGL(k_merge_ln, dim3(128), dim3(256), 0, stream,
                       ysb, gamma, beta, out);
}

// Round 5
// 108.286 us; speedup vs baseline: 6.3498x; 6.3498x over previous
//
#include <hip/hip_runtime.h>
#include <math.h>

#define D_ 96
#define L_ 4096
#define K_ 8
#define N_ 16
#define R_ 6
#define CDBL 38   // R + 2N
#define DL_ (D_ * L_)

#define REPN(M) M(0) M(1) M(2) M(3) M(4) M(5) M(6) M(7) \
                M(8) M(9) M(10) M(11) M(12) M(13) M(14) M(15)

__device__ __forceinline__ float softplusf(float x) {
    return (x > 20.f) ? x : log1pf(__expf(x));
}

// source index within one channel's [64][64] image for direction k, flat pos l
__device__ __forceinline__ int src_index(int k, int l) {
    int h = l & 63, w = l >> 6;
    int lp = 4095 - l;
    int hp = lp & 63, wp = lp >> 6;
    switch (k) {
    case 0: return l;
    case 1: return (h << 6) + w;
    case 2: return lp;
    case 3: return (hp << 6) + wp;
    case 4: return (h << 6) + ((h + w) & 63);
    case 5: return (h << 6) + ((w - h) & 63);
    case 6: return (hp << 6) + ((hp + wp) & 63);
    default: return (hp << 6) + ((wp - hp) & 63);
    }
}

// ---------------- K_A: x_dbl = wproj @ cross_scan(x), gathers x inline ----------
// grid 512 = 8 k * 64 l-tiles of 64; block 256
__global__ __launch_bounds__(256) void k_xdbl(const float* __restrict__ x,
                                              const float* __restrict__ wproj,
                                              float* __restrict__ xdbl) {
    __shared__ float tile[64][100];
    __shared__ float wlds[40 * D_];
    int bid = blockIdx.x;
    int swz = (bid & 7) * 64 + (bid >> 3);   // XCD swizzle: each XCD owns one k
    int k = swz >> 6;
    int l0 = (swz & 63) * 64;

    for (int e = threadIdx.x; e < 40 * D_; e += 256)
        wlds[e] = (e < CDBL * D_) ? wproj[k * CDBL * D_ + e] : 0.f;
    for (int e = threadIdx.x; e < D_ * 64; e += 256) {
        int d = e >> 6, li = e & 63;
        tile[li][d] = x[d * L_ + src_index(k, l0 + li)];
    }
    __syncthreads();

    int lt = threadIdx.x & 63;
    int cg = threadIdx.x >> 6;
    float acc[10];
    #pragma unroll
    for (int j = 0; j < 10; ++j) acc[j] = 0.f;
    for (int d4 = 0; d4 < D_; d4 += 4) {
        float4 tv = *(const float4*)&tile[lt][d4];
        #pragma unroll
        for (int j = 0; j < 10; ++j) {
            int c = cg + 4 * j;
            float4 wv = *(const float4*)&wlds[c * D_ + d4];
            acc[j] = fmaf(tv.x, wv.x, acc[j]);
            acc[j] = fmaf(tv.y, wv.y, acc[j]);
            acc[j] = fmaf(tv.z, wv.z, acc[j]);
            acc[j] = fmaf(tv.w, wv.w, acc[j]);
        }
    }
    #pragma unroll
    for (int j = 0; j < 10; ++j) {
        int c = cg + 4 * j;
        if (c < CDBL) xdbl[(k * CDBL + c) * L_ + l0 + lt] = acc[j];
    }
}

// ---------------- K_B: fused delta + selective scan (ALL-SCALAR state) --------
// grid 768, block 256, thread t owns l in [16t,16t+16).
// Rounds 2-4 lesson: float[16] locals (even literal-indexed, even by-ref into
// inlined helpers) were demoted to scratch (VGPR stuck at 84, ~1GB spill
// traffic). This version has ZERO hot arrays: d0..d15, u0..u15, y0..y15,
// sA0..sA15, sB0..sB15 are named scalars via token-pasting macros.
// Phase A: per-n (a,b) segment aggregates only (B rows). Phase B: batched DPP
// 64-lane scan. Phase C: cross-wave carry via LDS. Phase D: plain recurrence
// h=a*h+b, y+=C*h from carried-in h (B and C rows). Per-n memory fences cap
// the scheduler's load hoisting (pressure control).

#if __has_builtin(__builtin_amdgcn_update_dpp)
#define HAVE_DPP 1
template<int CTRL, int RM>
__device__ __forceinline__ float updpp(float oldv, float src) {
    int r = __builtin_amdgcn_update_dpp(__builtin_bit_cast(int, oldv),
                                        __builtin_bit_cast(int, src),
                                        CTRL, RM, 0xF, false);
    return __builtin_bit_cast(float, r);
}
#else
#define HAVE_DPP 0
#endif

__global__ __launch_bounds__(256, 3) void k_scan(const float* __restrict__ xdbl,
                                                 const float* __restrict__ dtw,
                                                 const float* __restrict__ dtb,
                                                 const float* __restrict__ alogs,
                                                 const float* __restrict__ dsv_,
                                                 const float* __restrict__ x,
                                                 float* __restrict__ ys) {
    int bid = blockIdx.x;
    int k = bid & 7;                 // XCD swizzle: k == XCD id
    int d = bid >> 3;
    int kd = k * D_ + d;
    int t = threadIdx.x;
    int lane = t & 63, wv = t >> 6;
    int l0t = t * 16;

    __shared__ float An_s[16];
    __shared__ float agg_a[4][16], agg_b[4][16];
    if (t < 16) An_s[t] = -expf(alogs[kd * N_ + t]);

#define DECL(n) float sA##n, sB##n;
    REPN(DECL)
#undef DECL
#define DECL(n) float d##n, u##n, y##n;
    REPN(DECL)
#undef DECL

    // ---- delta (fused) ----
    const float* xr = xdbl + k * CDBL * L_;
    const float2* wp2 = (const float2*)(dtw + kd * R_);
    const float2 w01 = wp2[0], w23 = wp2[1], w45 = wp2[2];
    const float bias = dtb[kd];
#define DLTQ(j, i0, i1, i2, i3) { \
    const float4 r0 = *(const float4*)(xr + 0 * L_ + l0t + j * 4); \
    const float4 r1 = *(const float4*)(xr + 1 * L_ + l0t + j * 4); \
    const float4 r2 = *(const float4*)(xr + 2 * L_ + l0t + j * 4); \
    const float4 r3 = *(const float4*)(xr + 3 * L_ + l0t + j * 4); \
    const float4 r4 = *(const float4*)(xr + 4 * L_ + l0t + j * 4); \
    const float4 r5 = *(const float4*)(xr + 5 * L_ + l0t + j * 4); \
    float s; \
    s = fmaf(w01.x, r0.x, bias); s = fmaf(w01.y, r1.x, s); s = fmaf(w23.x, r2.x, s); \
    s = fmaf(w23.y, r3.x, s); s = fmaf(w45.x, r4.x, s); s = fmaf(w45.y, r5.x, s); \
    d##i0 = softplusf(s); \
    s = fmaf(w01.x, r0.y, bias); s = fmaf(w01.y, r1.y, s); s = fmaf(w23.x, r2.y, s); \
    s = fmaf(w23.y, r3.y, s); s = fmaf(w45.x, r4.y, s); s = fmaf(w45.y, r5.y, s); \
    d##i1 = softplusf(s); \
    s = fmaf(w01.x, r0.z, bias); s = fmaf(w01.y, r1.z, s); s = fmaf(w23.x, r2.z, s); \
    s = fmaf(w23.y, r3.z, s); s = fmaf(w45.x, r4.z, s); s = fmaf(w45.y, r5.z, s); \
    d##i2 = softplusf(s); \
    s = fmaf(w01.x, r0.w, bias); s = fmaf(w01.y, r1.w, s); s = fmaf(w23.x, r2.w, s); \
    s = fmaf(w23.y, r3.w, s); s = fmaf(w45.x, r4.w, s); s = fmaf(w45.y, r5.w, s); \
    d##i3 = softplusf(s); }
    DLTQ(0, 0, 1, 2, 3)
    DLTQ(1, 4, 5, 6, 7)
    DLTQ(2, 8, 9, 10, 11)
    DLTQ(3, 12, 13, 14, 15)
#undef DLTQ

    // ---- u gather from x (1.5MB, L2/L3-resident); y zero-init ----
    const float* xd = x + d * L_;
#define UG(i) u##i = xd[src_index(k, l0t + i)]; y##i = 0.f;
    REPN(UG)
#undef UG

    __syncthreads();   // An_s ready

    const float* Bptr = xdbl + (k * CDBL + R_) * L_ + l0t;
    const float* Cptr = Bptr + N_ * L_;

    // ---- Phase A: per-n local (a,b) aggregates (B rows only) ----
#define PHA_E(i, Bc) { float a = __expf(d##i * An); \
    float b = d##i * (Bc) * u##i; \
    rb = fmaf(a, rb, b); ra *= a; }
#define PHA(n) { \
    const float An = An_s[n]; \
    const float* Bn = Bptr + n * L_; \
    const float4 b0 = *(const float4*)(Bn + 0), b1 = *(const float4*)(Bn + 4); \
    const float4 b2 = *(const float4*)(Bn + 8), b3 = *(const float4*)(Bn + 12); \
    float ra = 1.f, rb = 0.f; \
    PHA_E(0, b0.x) PHA_E(1, b0.y) PHA_E(2, b0.z) PHA_E(3, b0.w) \
    PHA_E(4, b1.x) PHA_E(5, b1.y) PHA_E(6, b1.z) PHA_E(7, b1.w) \
    PHA_E(8, b2.x) PHA_E(9, b2.y) PHA_E(10, b2.z) PHA_E(11, b2.w) \
    PHA_E(12, b3.x) PHA_E(13, b3.y) PHA_E(14, b3.z) PHA_E(15, b3.w) \
    sA##n = ra; sB##n = rb; \
    asm volatile("" ::: "memory"); }
    REPN(PHA)
#undef PHA
#undef PHA_E

    // ---- Phase B: 64-lane inclusive scan of 16 scalar (a,b) pairs ----
#if HAVE_DPP
#define SSTN(n) { float pa = updpp<SC_CTRL, SC_RM>(1.f, sA##n); \
                  float pb = updpp<SC_CTRL, SC_RM>(0.f, sB##n); \
                  sB##n = fmaf(sA##n, pb, sB##n); sA##n *= pa; }
#define SC_CTRL 0x111
#define SC_RM 0xF
    REPN(SSTN)            // row_shr:1
#undef SC_CTRL
#undef SC_RM
#define SC_CTRL 0x112
#define SC_RM 0xF
    REPN(SSTN)            // row_shr:2
#undef SC_CTRL
#undef SC_RM
#define SC_CTRL 0x114
#define SC_RM 0xF
    REPN(SSTN)            // row_shr:4
#undef SC_CTRL
#undef SC_RM
#define SC_CTRL 0x118
#define SC_RM 0xF
    REPN(SSTN)            // row_shr:8
#undef SC_CTRL
#undef SC_RM
#define SC_CTRL 0x142
#define SC_RM 0xA
    REPN(SSTN)            // row_bcast:15 -> rows 1,3
#undef SC_CTRL
#undef SC_RM
#define SC_CTRL 0x143
#define SC_RM 0xC
    REPN(SSTN)            // row_bcast:31 -> rows 2,3
#undef SC_CTRL
#undef SC_RM
#undef SSTN
#else
#define PBF(n) { float pa = __shfl_up(sA##n, off); float pb = __shfl_up(sB##n, off); \
    if (lane >= off) { sB##n = fmaf(sA##n, pb, sB##n); sA##n *= pa; } }
    for (int off = 1; off < 64; off <<= 1) { REPN(PBF) }
#undef PBF
#endif

    // exclusive prefix per lane + wave aggregates
#define PPREF(n) { float ia = sA##n, ib = sB##n; \
    float ea = __shfl_up(ia, 1); float eb = __shfl_up(ib, 1); \
    if (lane == 0) { ea = 1.f; eb = 0.f; } \
    if (lane == 63) { agg_a[wv][n] = ia; agg_b[wv][n] = ib; } \
    sA##n = ea; sB##n = eb; }
    REPN(PPREF)
#undef PPREF
    __syncthreads();

    // ---- Phase C: cross-wave carry -> h_enter per (thread, n), into sA ----
#define PC(n) { float cb = 0.f; \
    for (int w2 = 0; w2 < wv; ++w2) cb = fmaf(agg_a[w2][n], cb, agg_b[w2][n]); \
    sA##n = fmaf(sA##n, cb, sB##n); }
    REPN(PC)
#undef PC

    // ---- Phase D: plain recurrence from h_enter; y += C*h ----
#define PHD_E(i, Bc, Cc) { float a = __expf(d##i * An); \
    float b = d##i * (Bc) * u##i; \
    h = fmaf(a, h, b); y##i = fmaf((Cc), h, y##i); }
#define PHD(n) { \
    const float An = An_s[n]; float h = sA##n; \
    const float* Bn = Bptr + n * L_; const float* Cn = Cptr + n * L_; \
    const float4 b0 = *(const float4*)(Bn + 0), b1 = *(const float4*)(Bn + 4); \
    const float4 b2 = *(const float4*)(Bn + 8), b3 = *(const float4*)(Bn + 12); \
    const float4 c0 = *(const float4*)(Cn + 0), c1 = *(const float4*)(Cn + 4); \
    const float4 c2 = *(const float4*)(Cn + 8), c3 = *(const float4*)(Cn + 12); \
    PHD_E(0, b0.x, c0.x) PHD_E(1, b0.y, c0.y) PHD_E(2, b0.z, c0.z) PHD_E(3, b0.w, c0.w) \
    PHD_E(4, b1.x, c1.x) PHD_E(5, b1.y, c1.y) PHD_E(6, b1.z, c1.z) PHD_E(7, b1.w, c1.w) \
    PHD_E(8, b2.x, c2.x) PHD_E(9, b2.y, c2.y) PHD_E(10, b2.z, c2.z) PHD_E(11, b2.w, c2.w) \
    PHD_E(12, b3.x, c3.x) PHD_E(13, b3.y, c3.y) PHD_E(14, b3.z, c3.z) PHD_E(15, b3.w, c3.w) \
    asm volatile("" ::: "memory"); }
    REPN(PHD)
#undef PHD
#undef PHD_E

    const float dval = dsv_[kd];
#define YD(i) y##i = fmaf(dval, u##i, y##i);
    REPN(YD)
#undef YD
    float* yp = ys + kd * L_ + l0t;
    {
        float4 o;
        o.x = y0;  o.y = y1;  o.z = y2;  o.w = y3;  *(float4*)(yp + 0)  = o;
        o.x = y4;  o.y = y5;  o.z = y6;  o.w = y7;  *(float4*)(yp + 4)  = o;
        o.x = y8;  o.y = y9;  o.z = y10; o.w = y11; *(float4*)(yp + 8)  = o;
        o.x = y12; o.y = y13; o.z = y14; o.w = y15; *(float4*)(yp + 12) = o;
    }
}

// ---------------- K_C: cross_merge + LayerNorm fused ----------------
// grid 128 blocks x 32 positions; block 256
__global__ __launch_bounds__(256) void k_merge_ln(const float* __restrict__ ys,
                                                  const float* __restrict__ gamma,
                                                  const float* __restrict__ beta,
                                                  float* __restrict__ out) {
    __shared__ float sm[32][D_ + 1];
    __shared__ float mu_s[32], rs_s[32];
    int l0 = blockIdx.x * 32;
    for (int e = threadIdx.x; e < 32 * D_; e += 256) {
        int li = e & 31, d = e >> 5;
        int l = l0 + li;
        int h = l >> 6, w = l & 63;
        int i1 = (w << 6) + h;
        int i4 = (((w - h) & 63) << 6) + h;
        int i5 = (((w + h) & 63) << 6) + h;
        const float* bd = ys + d * L_;
        float v = bd[0 * DL_ + l] + bd[2 * DL_ + 4095 - l]
                + bd[1 * DL_ + i1] + bd[3 * DL_ + 4095 - i1]
                + bd[4 * DL_ + i4] + bd[6 * DL_ + 4095 - i4]
                + bd[5 * DL_ + i5] + bd[7 * DL_ + 4095 - i5];
        sm[li][d] = v;
    }
    __syncthreads();
    int li2 = threadIdx.x >> 3, sub = threadIdx.x & 7;
    float s = 0.f, sq = 0.f;
    for (int d = sub; d < D_; d += 8) {
        float v = sm[li2][d];
        s += v; sq = fmaf(v, v, sq);
    }
    s += __shfl_xor(s, 1); sq += __shfl_xor(sq, 1);
    s += __shfl_xor(s, 2); sq += __shfl_xor(sq, 2);
    s += __shfl_xor(s, 4); sq += __shfl_xor(sq, 4);
    if (sub == 0) {
        float mu = s * (1.f / 96.f);
        float var = sq * (1.f / 96.f) - mu * mu;
        mu_s[li2] = mu;
        rs_s[li2] = rsqrtf(var + 1e-5f);
    }
    __syncthreads();
    for (int e = threadIdx.x; e < 32 * D_; e += 256) {
        int li = e / D_, d = e - li * D_;
        float v = (sm[li][d] - mu_s[li]) * rs_s[li];
        out[(l0 + li) * D_ + d] = fmaf(v, gamma[d], beta[d]);
    }
}

extern "C" void kernel_launch(void* const* d_in, const int* in_sizes, int n_in,
                              void* d_out, int out_size, void* d_ws, size_t ws_size,
                              hipStream_t stream) {
    const float* x     = (const float*)d_in[0];
    const float* wproj = (const float*)d_in[1];
    const float* dtw   = (const float*)d_in[2];
    const float* dtb   = (const float*)d_in[3];
    const float* alogs = (const float*)d_in[4];
    const float* dsv   = (const float*)d_in[5];
    const float* gamma = (const float*)d_in[6];
    const float* beta  = (const float*)d_in[7];
    float* out = (float*)d_out;
    float* ws  = (float*)d_ws;

    float* xdbl = ws;                 // K*CDBL*L = 1,245,184 floats
    float* ysb  = ws + 1245184;       // K*D*L    = 3,145,728 floats

    hipLaunchKernelGGL(k_xdbl, dim3(512), dim3(256), 0, stream, x, wproj, xdbl);
    hipLaunchKernelGGL(k_scan, dim3(768), dim3(256), 0, stream,
                       xdbl, dtw, dtb, alogs, dsv, x, ysb);
    hipLaunchKernelGGL(k_merge_ln, dim3(128), dim3(256), 0, stream,
                       ysb, gamma, beta, out);
}